// Round 6
// baseline (134.187 us; speedup 1.0000x reference)
//
#include <hip/hip_runtime.h>
#include <hip/hip_bf16.h>

#define EMB 128
#define HID 11
#define PAIRS 2   // pair-units per group; group = 4 consecutive tokens

typedef float f32x4 __attribute__((ext_vector_type(4)));

// tanh(x) = sign(x) * (1 - 2/(exp(2|x|)+1)); v_exp_f32 + v_rcp_f32 fast path.
__device__ __forceinline__ float fast_tanh(float x) {
    float ax = fabsf(x);
    float e  = __expf(2.0f * ax);
    float r  = 1.0f - 2.0f * __builtin_amdgcn_rcpf(e + 1.0f);
    return copysignf(r, x);
}

// R5 lesson: latency-hiding tweaks are flat at ~95us -> limiter is the write
// path. This version changes token->wave ownership from strided to
// CONTIGUOUS: wave i owns tokens [i*tpw, (i+1)*tpw), processing 4 tokens per
// iteration -> each iteration stores 2KB contiguous and successive
// iterations append sequentially (51KB sequential stream per wave, good DRAM
// page locality). Stores are plain (no nt hint) — the 6.9TB/s fill kernel
// uses plain stores.
// Wave layout per pair-unit: lanes 0..31 -> token t, lanes 32..63 -> t+1;
// lane covers 4 emb columns, c0=(lane&31)*4. One fast-tanh per token, h
// broadcast via __shfl in the half-wave. 1-stage software pipeline (R5).
// __launch_bounds__(256,2): ~110 VGPRs live, no spill (R3 lesson).
__global__ __launch_bounds__(256, 2) void tabenc_kernel(
    const float* __restrict__ value,
    const int*   __restrict__ var_id,
    const int*   __restrict__ cmask,
    const float* __restrict__ W1,
    const float* __restrict__ b1,
    const float* __restrict__ W2,
    const float* __restrict__ emb,
    float*       __restrict__ out_sum,
    float*       __restrict__ out_pm,
    int n_tokens, int tpw)
{
    const int tid  = threadIdx.x;
    const int lane = tid & 63;
    const int half = lane >> 5;
    const int sub  = lane & 31;
    const int sb   = lane & 32;      // shfl source base for this half-wave
    const int c0   = sub << 2;

    f32x4 w2[HID];
#pragma unroll
    for (int h = 0; h < HID; ++h)
        w2[h] = *reinterpret_cast<const f32x4*>(W2 + h * EMB + c0);

    float w1v = 0.0f, b1v = 0.0f;
    if (sub < HID) { w1v = W1[sub]; b1v = b1[sub]; }

    const int gwave = (blockIdx.x << 2) + (tid >> 6);
    const int base  = gwave * tpw;           // first token this wave owns
    if (base >= n_tokens) return;
    const int tmax  = n_tokens - 1;
    const int ngrp  = (tpw + 3) >> 2;        // 4 tokens per group

    int   tokC[PAIRS]; bool actC[PAIRS]; float vC[PAIRS];
    int   idC[PAIRS];  float fmC[PAIRS];  f32x4 eC[PAIRS];
    int   tokN[PAIRS]; bool actN[PAIRS]; float vN[PAIRS];
    int   idN[PAIRS];  float fmN[PAIRS];  f32x4 eN[PAIRS];

    auto LOAD = [&](int g, int* tok, bool* act, float* v, int* id,
                    float* fm, f32x4* e) {
#pragma unroll
        for (int k = 0; k < PAIRS; ++k) {
            int t = base + (g << 2) + (k << 1) + half;
            act[k] = (t < n_tokens);
            if (t > tmax) t = tmax;          // clamp: branch-free dup loads
            tok[k] = t;
            v[k]  = value[t];
            id[k] = var_id[t];
            fm[k] = (float)cmask[t];
        }
#pragma unroll
        for (int k = 0; k < PAIRS; ++k)
            e[k] = *reinterpret_cast<const f32x4*>(emb + (long)id[k] * EMB + c0);
    };

    LOAD(0, tokC, actC, vC, idC, fmC, eC);

    for (int g = 0; g < ngrp; ++g) {
        // ---- prefetch next group (clamped, unconditional) ----
        LOAD(g + 1 < ngrp ? g + 1 : g, tokN, actN, vN, idN, fmN, eN);

        // ---- compute current group ----
        float hv[PAIRS];
#pragma unroll
        for (int k = 0; k < PAIRS; ++k)
            hv[k] = fast_tanh(fmaf(vC[k], w1v, b1v));

        f32x4 acc[PAIRS];
#pragma unroll
        for (int k = 0; k < PAIRS; ++k)
            acc[k] = (f32x4){0.f, 0.f, 0.f, 0.f};

#pragma unroll
        for (int hh = 0; hh < HID; ++hh) {
#pragma unroll
            for (int k = 0; k < PAIRS; ++k) {
                const float kk = __shfl(hv[k], sb + hh, 64);
                acc[k] += kk * w2[hh];
            }
        }

#pragma unroll
        for (int k = 0; k < PAIRS; ++k) {
            if (actC[k]) {
                const f32x4 o = acc[k] * fmC[k] + eC[k];
                *reinterpret_cast<f32x4*>(out_sum + (long)tokC[k] * EMB + c0) = o;
                if (sub == 0)
                    out_pm[tokC[k]] = (idC[k] > 0) ? 1.0f : 0.0f;
            }
        }

        // ---- rotate pipeline regs ----
#pragma unroll
        for (int k = 0; k < PAIRS; ++k) {
            tokC[k] = tokN[k]; actC[k] = actN[k]; vC[k] = vN[k];
            idC[k]  = idN[k];  fmC[k]  = fmN[k];  eC[k] = eN[k];
        }
    }
}

extern "C" void kernel_launch(void* const* d_in, const int* in_sizes, int n_in,
                              void* d_out, int out_size, void* d_ws, size_t ws_size,
                              hipStream_t stream) {
    const float* value  = (const float*)d_in[0];
    const int*   var_id = (const int*)  d_in[1];
    const int*   cmask  = (const int*)  d_in[2];
    const float* W1     = (const float*)d_in[3];
    const float* b1     = (const float*)d_in[4];
    const float* W2     = (const float*)d_in[5];
    const float* emb    = (const float*)d_in[6];

    const int n_tokens = in_sizes[0];              // 4096*200 = 819200
    float* out_sum = (float*)d_out;                // [n_tokens, 128]
    float* out_pm  = (float*)d_out + (long long)n_tokens * EMB;  // [n_tokens]

    const int nwaves = 2048 * 4;                   // 2048 blocks x 4 waves
    int tpw = (n_tokens + nwaves - 1) / nwaves;    // tokens per wave
    tpw = (tpw + 3) & ~3;                          // multiple of 4
    int blocks = (n_tokens + tpw * 4 - 1) / (tpw * 4);
    if (blocks > 2048) blocks = 2048;

    tabenc_kernel<<<blocks, 256, 0, stream>>>(value, var_id, cmask, W1, b1, W2,
                                              emb, out_sum, out_pm,
                                              n_tokens, tpw);
}